// Round 1
// baseline (49.089 us; speedup 1.0000x reference)
//
#include <hip/hip_runtime.h>
#include <hip/hip_bf16.h>

typedef __bf16 bf16x8 __attribute__((ext_vector_type(8)));
typedef float f32x4 __attribute__((ext_vector_type(4)));

#define G 8
#define B 32
#define D 32
#define O 32
#define K 4096   // N*T
#define T 64
#define KSPLIT 4
#define KCHUNK (K / KSPLIT)  // 1024

// ws layout: [0, 8MB): XMT bf16 [O][B][K]; then S f32 [KSPLIT][G][O][D][B] (4 MB)
#define XMT_ELEMS (O * B * K)              // 4,194,304 bf16 = 8 MB
#define S_ELEMS   (KSPLIT * G * O * D * B) // 1,048,576 f32  = 4 MB

// XMT[o][b][k] = x[b][k] * mask[o][k%64], as bf16. k = n*64+t, x is [b][n][t] so
// flat x index == b*K + k.
__global__ __launch_bounds__(256) void prep_xmt(const float* __restrict__ x,
                                                const float* __restrict__ mask,
                                                __bf16* __restrict__ xmt) {
    int tid = blockIdx.x * 256 + threadIdx.x;   // 524288 threads, 8 elems each
    int o = tid >> 14;
    int b = (tid >> 9) & 31;
    int k = (tid & 511) << 3;
    int t = k & 63;
    const float4 x0 = *(const float4*)(x + b * K + k);
    const float4 x1 = *(const float4*)(x + b * K + k + 4);
    const float4 m0 = *(const float4*)(mask + o * T + t);
    const float4 m1 = *(const float4*)(mask + o * T + t + 4);
    bf16x8 r;
    r[0] = (__bf16)(x0.x * m0.x); r[1] = (__bf16)(x0.y * m0.y);
    r[2] = (__bf16)(x0.z * m0.z); r[3] = (__bf16)(x0.w * m0.w);
    r[4] = (__bf16)(x1.x * m1.x); r[5] = (__bf16)(x1.y * m1.y);
    r[6] = (__bf16)(x1.z * m1.z); r[7] = (__bf16)(x1.w * m1.w);
    *(bf16x8*)(xmt + (size_t)(o * B + b) * K + k) = r;
}

// S[ks][g][o][d][b] = sum over k in ks-chunk of W[g][d][o][k] * XMT[o][b][k]
// Block = (o, g, ks), 128 threads = 2 waves; wave w covers d in [16w, 16w+16).
// MFMA 16x16x32 bf16: A = W tile (m=d), B = XMT tile (n=b, two halves).
__global__ __launch_bounds__(128) void gemm_main(const float* __restrict__ W,
                                                 const __bf16* __restrict__ xmt,
                                                 float* __restrict__ S) {
    const int o = blockIdx.x, g = blockIdx.y, ks = blockIdx.z;
    const int wave = threadIdx.x >> 6;
    const int lane = threadIdx.x & 63;
    const int dbase = wave * 16;
    const int d = dbase + (lane & 15);
    const int klane = (lane >> 4) * 8;

    const float*  wrow = W + (size_t)((g * D + d) * O + o) * K + ks * KCHUNK + klane;
    const __bf16* xr0  = xmt + (size_t)(o * B + (lane & 15)) * K + ks * KCHUNK + klane;
    const __bf16* xr1  = xr0 + (size_t)16 * K;

    f32x4 acc0 = {0.f, 0.f, 0.f, 0.f};
    f32x4 acc1 = {0.f, 0.f, 0.f, 0.f};

    #pragma unroll 4
    for (int s = 0; s < KCHUNK / 32; ++s) {
        const float4 wa = *(const float4*)(wrow + s * 32);
        const float4 wb = *(const float4*)(wrow + s * 32 + 4);
        bf16x8 af;
        af[0] = (__bf16)wa.x; af[1] = (__bf16)wa.y;
        af[2] = (__bf16)wa.z; af[3] = (__bf16)wa.w;
        af[4] = (__bf16)wb.x; af[5] = (__bf16)wb.y;
        af[6] = (__bf16)wb.z; af[7] = (__bf16)wb.w;
        const bf16x8 bf0 = *(const bf16x8*)(xr0 + s * 32);
        const bf16x8 bf1 = *(const bf16x8*)(xr1 + s * 32);
        acc0 = __builtin_amdgcn_mfma_f32_16x16x32_bf16(af, bf0, acc0, 0, 0, 0);
        acc1 = __builtin_amdgcn_mfma_f32_16x16x32_bf16(af, bf1, acc1, 0, 0, 0);
    }

    // C/D layout (m89-verified): lane holds D[row=(lane>>4)*4+r][col=lane&15]
    float* Sp = S + (size_t)(((ks * G + g) * O + o) * D + dbase) * B;
    const int r0 = (lane >> 4) * 4, c = lane & 15;
    #pragma unroll
    for (int r = 0; r < 4; ++r) {
        Sp[(r0 + r) * B + c]      = acc0[r];
        Sp[(r0 + r) * B + 16 + c] = acc1[r];
    }
}

// out[b][d][o] = bias[d][o] + sum_g y[b][g] * sum_ks S[ks][g][o][d][b]
__global__ __launch_bounds__(256) void reduce_out(const float* __restrict__ S,
                                                  const float* __restrict__ y,
                                                  const float* __restrict__ bias,
                                                  float* __restrict__ out) {
    int tid = blockIdx.x * 256 + threadIdx.x;   // 32768 = B*D*O
    int o = tid & 31, d = (tid >> 5) & 31, b = tid >> 10;
    float acc = bias[d * O + o];
    #pragma unroll
    for (int g = 0; g < G; ++g) {
        float s = 0.f;
        #pragma unroll
        for (int ks = 0; ks < KSPLIT; ++ks)
            s += S[(size_t)(((ks * G + g) * O + o) * D + d) * B + b];
        acc += y[b * G + g] * s;
    }
    out[tid] = acc;
}

extern "C" void kernel_launch(void* const* d_in, const int* in_sizes, int n_in,
                              void* d_out, int out_size, void* d_ws, size_t ws_size,
                              hipStream_t stream) {
    const float* x    = (const float*)d_in[0];
    const float* y    = (const float*)d_in[1];
    const float* w    = (const float*)d_in[2];
    const float* bias = (const float*)d_in[3];
    const float* mask = (const float*)d_in[4];
    float* out = (float*)d_out;

    __bf16* xmt = (__bf16*)d_ws;
    float*  S   = (float*)((char*)d_ws + (size_t)XMT_ELEMS * sizeof(__bf16));

    prep_xmt<<<2048, 256, 0, stream>>>(x, mask, xmt);
    gemm_main<<<dim3(O, G, KSPLIT), 128, 0, stream>>>(w, xmt, S);
    reduce_out<<<128, 256, 0, stream>>>(S, y, bias, out);
}